// Round 6
// baseline (695.710 us; speedup 1.0000x reference)
//
#include <hip/hip_runtime.h>
#include <hip/hip_bf16.h>
#include <stdint.h>

#define D 512
#define BATCH 256
#define SEQ 512
// M = BATCH*SEQ = 131072

typedef __attribute__((ext_vector_type(8))) short short8;
typedef __attribute__((ext_vector_type(4))) float floatx4;

__device__ __forceinline__ float bf2f(unsigned short u) {
    union { unsigned int i; float f; } x; x.i = ((unsigned int)u) << 16; return x.f;
}
__device__ __forceinline__ unsigned short f2bf(float f) {
    union { float f; unsigned int i; } x; x.f = f;
    unsigned int i = x.i;
    unsigned int lsb = (i >> 16) & 1u;
    i += 0x7fffu + lsb;
    return (unsigned short)(i >> 16);
}

__device__ __forceinline__ float wred_sum(float v) {
    #pragma unroll
    for (int o = 32; o; o >>= 1) v += __shfl_xor(v, o, 64);
    return v;
}

__device__ __forceinline__ void llds16(const void* g, void* l) {
    auto gp = (const __attribute__((address_space(1))) void*)(g);
    auto lp = (__attribute__((address_space(3))) void*)(uintptr_t)(l);
    __builtin_amdgcn_global_load_lds(gp, lp, 16, 0, 0);
}

// ---------------- fused scores + softmax: one block per batch, 512 threads ----------------
template<bool F32IN>
__global__ __launch_bounds__(512)
void scores_kernel(const void* __restrict__ s_in_, const float* __restrict__ q,
                   float* __restrict__ dist_out, unsigned short* __restrict__ s_bf_out) {
    const int b = blockIdx.x, t = threadIdx.x, lane = t & 63, w = t >> 6;
    __shared__ float sc[SEQ];
    __shared__ float red[8];
    __shared__ float m_s, sum_s;

    float qv[8];
    {
        const float4* qp = (const float4*)(q + (size_t)b * D + lane * 8);
        float4 a = qp[0], c = qp[1];
        qv[0] = a.x; qv[1] = a.y; qv[2] = a.z; qv[3] = a.w;
        qv[4] = c.x; qv[5] = c.y; qv[6] = c.z; qv[7] = c.w;
    }
    float qn2 = 0.f;
    #pragma unroll
    for (int j = 0; j < 8; ++j) qn2 += qv[j] * qv[j];
    const float qn = sqrtf(wred_sum(qn2));

    const size_t bbase = (size_t)b * (SEQ * D);
    // each wave handles rows [w*64, w*64+64), two at a time for load depth
    for (int j = 0; j < 64; j += 2) {
        const int r0 = w * 64 + j;
        float v0[8], v1[8];
        const size_t off0 = bbase + (size_t)r0 * D + lane * 8;
        const size_t off1 = off0 + D;
        if (F32IN) {
            const float4* p0 = (const float4*)((const float*)s_in_ + off0);
            const float4* p1 = (const float4*)((const float*)s_in_ + off1);
            float4 a0 = p0[0], c0 = p0[1], a1 = p1[0], c1 = p1[1];
            v0[0]=a0.x; v0[1]=a0.y; v0[2]=a0.z; v0[3]=a0.w;
            v0[4]=c0.x; v0[5]=c0.y; v0[6]=c0.z; v0[7]=c0.w;
            v1[0]=a1.x; v1[1]=a1.y; v1[2]=a1.z; v1[3]=a1.w;
            v1[4]=c1.x; v1[5]=c1.y; v1[6]=c1.z; v1[7]=c1.w;
            short8 w0, w1;
            #pragma unroll
            for (int k = 0; k < 8; ++k) { w0[k] = (short)f2bf(v0[k]); w1[k] = (short)f2bf(v1[k]); }
            *(short8*)(s_bf_out + off0) = w0;
            *(short8*)(s_bf_out + off1) = w1;
        } else {
            short8 w0 = *(const short8*)((const unsigned short*)s_in_ + off0);
            short8 w1 = *(const short8*)((const unsigned short*)s_in_ + off1);
            #pragma unroll
            for (int k = 0; k < 8; ++k) { v0[k] = bf2f((unsigned short)w0[k]); v1[k] = bf2f((unsigned short)w1[k]); }
        }
        float d0 = 0.f, n0 = 0.f, d1 = 0.f, n1 = 0.f;
        #pragma unroll
        for (int k = 0; k < 8; ++k) {
            d0 += v0[k] * qv[k]; n0 += v0[k] * v0[k];
            d1 += v1[k] * qv[k]; n1 += v1[k] * v1[k];
        }
        d0 = wred_sum(d0); n0 = wred_sum(n0);
        d1 = wred_sum(d1); n1 = wred_sum(n1);
        if (lane == 0) {
            sc[r0]     = 10.f * d0 / fmaxf(qn * sqrtf(n0), 1e-8f);
            sc[r0 + 1] = 10.f * d1 / fmaxf(qn * sqrtf(n1), 1e-8f);
        }
    }
    __syncthreads();

    // softmax over sc[512], one element per thread
    const float sv = sc[t];
    float m = sv;
    #pragma unroll
    for (int o = 32; o; o >>= 1) m = fmaxf(m, __shfl_xor(m, o, 64));
    if (lane == 0) red[w] = m;
    __syncthreads();
    if (t == 0) {
        float mm = red[0];
        #pragma unroll
        for (int k = 1; k < 8; ++k) mm = fmaxf(mm, red[k]);
        m_s = mm;
    }
    __syncthreads();
    const float e = __expf(sv - m_s);
    float es = wred_sum(e);
    if (lane == 0) red[w] = es;
    __syncthreads();
    if (t == 0) {
        float s = 0.f;
        #pragma unroll
        for (int k = 0; k < 8; ++k) s += red[k];
        sum_s = s;
    }
    __syncthreads();
    dist_out[b * SEQ + t] = e / sum_s;
}

// ---------------- GEMM: C = lrelu(A @ W^T + bias), direct agg write ----------------
// Persistent: grid = 256 blocks (1/CU), 512 threads (8 waves).  Each block:
//  - n_tile (128 cols) x m_chunk (2048 rows); XCD-aware mapping so the 4 n-tiles
//    sharing A rows land on one XCD (L2 shares the A stream).
//  - B panel (128x512) staged in LDS ONCE (swizzled, rule#21); single barrier.
//  - A streamed global->VGPR, 8-deep static register ring (no K-loop barriers;
//    backend register scoreboard provides precise waits).
//  - block owns complete (batch,col) agg sums -> writes agg directly.
__global__ __launch_bounds__(512, 2)
void gemm_kernel(const unsigned short* __restrict__ A, const unsigned short* __restrict__ Bt,
                 const float* __restrict__ bias, const float* __restrict__ dist,
                 unsigned short* __restrict__ C, float* __restrict__ agg) {
    __shared__ __align__(16) unsigned short Bs[128 * 512];   // 128 KB
    __shared__ float dls[2048];                               // 8 KB
    __shared__ float agg_lds[4][4][128];                      // 8 KB

    const int t = threadIdx.x, lane = t & 63, w = t >> 6;
    const int wm = w >> 1, wn = w & 1;
    const int rr = lane & 15, lg = lane >> 4;
    const int bid = blockIdx.x;
    const int xcd = bid & 7, slot = bid >> 3;
    const int n_tile = slot & 3, m_sub = slot >> 2;
    const int tileN = n_tile * 128;
    const int m_chunk = xcd * 8 + m_sub;
    const size_t tileM = (size_t)m_chunk * 2048;

    // A stream pointers (per wave: rows wm*64 + mi*16 + rr of current 256-row strip)
    const unsigned short* curA[4];
    const unsigned short* nxtA[4];
    #pragma unroll
    for (int mi = 0; mi < 4; ++mi) {
        curA[mi] = A + (tileM + (size_t)(wm * 64 + mi * 16 + rr)) * D + lg * 8;
        nxtA[mi] = curA[mi] + 256 * D;
    }

    // prologue: prefetch kt 0..7 of strip 0
    short8 ring[8][4];
    #pragma unroll
    for (int kt = 0; kt < 8; ++kt)
        #pragma unroll
        for (int mi = 0; mi < 4; ++mi)
            ring[kt][mi] = *(const short8*)(curA[mi] + kt * 32);

    float b_r[4];
    #pragma unroll
    for (int ni = 0; ni < 4; ++ni) b_r[ni] = bias[tileN + wn * 64 + ni * 16 + rr];

    // stage B panel (swizzled: LDS chunk (col, pc) holds global chunk pc ^ (col&7))
    #pragma unroll
    for (int it = 0; it < 16; ++it) {
        const int f = it * 512 + t;
        const int col = f >> 6, pc = f & 63;
        const int gc = pc ^ (col & 7);
        llds16(Bt + (size_t)(tileN + col) * D + gc * 8, (unsigned short*)Bs + (size_t)f * 8);
    }
    *(float4*)&dls[t * 4] = *(const float4*)&dist[tileM + t * 4];
    __syncthreads();   // only block-wide barrier before the end

    float pacc[4] = {0.f, 0.f, 0.f, 0.f};

    for (int i = 0; i < 8; ++i) {            // 8 strips of 256 rows
        floatx4 acc[4][4];
        #pragma unroll
        for (int mi = 0; mi < 4; ++mi)
            #pragma unroll
            for (int ni = 0; ni < 4; ++ni) acc[mi][ni] = {0.f, 0.f, 0.f, 0.f};

        #pragma unroll
        for (int kt = 0; kt < 16; ++kt) {
            const int sl = kt & 7;
            #pragma unroll
            for (int ni = 0; ni < 4; ++ni) {
                const short8 bfr = *(const short8*)&Bs[(wn * 64 + ni * 16 + rr) * D +
                                                       (((kt * 4 + lg) ^ (rr & 7)) << 3)];
                #pragma unroll
                for (int mi = 0; mi < 4; ++mi)
                    acc[mi][ni] = __builtin_amdgcn_mfma_f32_16x16x32_bf16(ring[sl][mi], bfr, acc[mi][ni], 0, 0, 0);
            }
            if (kt < 8) {                    // refill slot with kt+8 of current strip
                #pragma unroll
                for (int mi = 0; mi < 4; ++mi)
                    ring[sl][mi] = *(const short8*)(curA[mi] + (kt + 8) * 32);
            } else if (i < 7) {              // prefetch kt-8 of next strip
                #pragma unroll
                for (int mi = 0; mi < 4; ++mi)
                    ring[sl][mi] = *(const short8*)(nxtA[mi] + (kt - 8) * 32);
            }
        }

        // strip epilogue: bias + lrelu + store + agg partial
        #pragma unroll
        for (int mi = 0; mi < 4; ++mi) {
            const int rl = i * 256 + wm * 64 + mi * 16 + lg * 4;
            const float4 dv = *(const float4*)&dls[rl];
            #pragma unroll
            for (int ni = 0; ni < 4; ++ni) {
                const int col = tileN + wn * 64 + ni * 16 + rr;
                #pragma unroll
                for (int r2 = 0; r2 < 4; ++r2) {
                    float v = acc[mi][ni][r2] + b_r[ni];
                    v = v >= 0.f ? v : 0.01f * v;
                    C[(tileM + rl + r2) * D + col] = f2bf(v);
                    pacc[ni] += (&dv.x)[r2] * v;
                }
            }
        }
        if (i & 1) {                          // batch boundary (2 strips = 512 rows)
            const int batch = i >> 1;
            #pragma unroll
            for (int ni = 0; ni < 4; ++ni) {
                float p = pacc[ni];
                p += __shfl_xor(p, 16, 64);
                p += __shfl_xor(p, 32, 64);
                if (lg == 0) agg_lds[wm][batch][wn * 64 + ni * 16 + rr] = p;
                pacc[ni] = 0.f;
            }
        }
        #pragma unroll
        for (int mi = 0; mi < 4; ++mi) { curA[mi] = nxtA[mi]; nxtA[mi] += 256 * D; }
    }

    __syncthreads();
    {
        const int bb = t >> 7, col = t & 127;
        const float s = agg_lds[0][bb][col] + agg_lds[1][bb][col] +
                        agg_lds[2][bb][col] + agg_lds[3][bb][col];
        agg[(size_t)(m_chunk * 4 + bb) * D + tileN + col] = s;
    }
}

// ---------------- agg + residual + LayerNorm ----------------
__global__ __launch_bounds__(256)
void aggln_kernel(const float* __restrict__ agg, const float* __restrict__ q_in,
                  const float* __restrict__ gamma, const float* __restrict__ beta,
                  float* __restrict__ q_out) {
    const int b = blockIdx.x, t = threadIdx.x, lane = t & 63, wv = t >> 6;
    __shared__ float red[8];
    __shared__ float mu_s, rstd_s;

    const int c0 = 2 * t;
    const float2 av = *(const float2*)(agg + (size_t)b * D + c0);
    float x0 = q_in[b * D + c0] + av.x;
    float x1 = q_in[b * D + c0 + 1] + av.y;

    float sm = wred_sum(x0 + x1);
    if (lane == 0) red[wv] = sm;
    __syncthreads();
    if (t == 0) mu_s = (red[0] + red[1] + red[2] + red[3]) * (1.f / 512.f);
    __syncthreads();
    const float mu = mu_s;
    float d0 = x0 - mu, d1 = x1 - mu;
    float vv = wred_sum(d0 * d0 + d1 * d1);
    if (lane == 0) red[wv] = vv;
    __syncthreads();
    if (t == 0) rstd_s = rsqrtf((red[0] + red[1] + red[2] + red[3]) * (1.f / 512.f) + 1e-5f);
    __syncthreads();
    const float rs = rstd_s;
    q_out[b * D + c0]     = d0 * rs * gamma[c0]     + beta[c0];
    q_out[b * D + c0 + 1] = d1 * rs * gamma[c0 + 1] + beta[c0 + 1];
}

// ---------------- W f32 -> bf16 ----------------
__global__ __launch_bounds__(256)
void convw_kernel(const float* __restrict__ W, unsigned short* __restrict__ Wb, int n4) {
    int i = blockIdx.x * 256 + threadIdx.x;
    if (i < n4) {
        float4 v = *(const float4*)(W + (size_t)i * 4);
        ushort4 o;
        o.x = f2bf(v.x); o.y = f2bf(v.y); o.z = f2bf(v.z); o.w = f2bf(v.w);
        *(ushort4*)(Wb + (size_t)i * 4) = o;
    }
}

extern "C" void kernel_launch(void* const* d_in, const int* in_sizes, int n_in,
                              void* d_out, int out_size, void* d_ws, size_t ws_size,
                              hipStream_t stream) {
    const float* query = (const float*)d_in[0];
    const float* state = (const float*)d_in[1];
    const float* W     = (const float*)d_in[2];
    const float* bias  = (const float*)d_in[3];
    const float* gamma = (const float*)d_in[4];
    const float* beta  = (const float*)d_in[5];

    float* out_q    = (float*)d_out;
    float* out_dist = (float*)d_out + BATCH * SEQ;

    char* ws = (char*)d_ws;
    const size_t SBYTES = (size_t)BATCH * SEQ * D * 2;   // 134,217,728
    unsigned short* sA = (unsigned short*)ws;
    unsigned short* sB = (unsigned short*)(ws + SBYTES);
    char* ext = ws + 2 * SBYTES;
    float* dist = (float*)ext;                           // 512 KB
    float* qbuf = (float*)(ext + 524288);                // 512 KB
    float* agg  = (float*)(ext + 2 * 524288);            // 512 KB
    unsigned short* Wb = (unsigned short*)(ext + 3 * 524288);  // 1.5 MB

    hipMemcpyAsync(qbuf, query, (size_t)BATCH * D * sizeof(float),
                   hipMemcpyDeviceToDevice, stream);
    convw_kernel<<<768, 256, 0, stream>>>(W, Wb, 3 * D * D / 4);

    // hop 0
    scores_kernel<true><<<BATCH, 512, 0, stream>>>(state, qbuf, dist, sA);
    gemm_kernel<<<256, 512, 0, stream>>>(sA, Wb, bias, dist, sB, agg);
    aggln_kernel<<<BATCH, 256, 0, stream>>>(agg, qbuf, gamma, beta, qbuf);
    // hop 1
    scores_kernel<false><<<BATCH, 512, 0, stream>>>(sB, qbuf, dist, nullptr);
    gemm_kernel<<<256, 512, 0, stream>>>(sB, Wb + D * D, bias + D, dist, sA, agg);
    aggln_kernel<<<BATCH, 256, 0, stream>>>(agg, qbuf, gamma, beta, qbuf);
    // hop 2
    scores_kernel<false><<<BATCH, 512, 0, stream>>>(sA, qbuf, dist, nullptr);
    gemm_kernel<<<256, 512, 0, stream>>>(sA, Wb + 2 * D * D, bias + 2 * D, dist, sB, agg);
    aggln_kernel<<<BATCH, 256, 0, stream>>>(agg, qbuf, gamma, beta, out_q);
    // final dist
    scores_kernel<false><<<BATCH, 512, 0, stream>>>(sB, out_q, out_dist, nullptr);
}

// Round 7
// 489.830 us; speedup vs baseline: 1.4203x; 1.4203x over previous
//
#include <hip/hip_runtime.h>
#include <hip/hip_bf16.h>
#include <stdint.h>

#define D 512
#define BATCH 256
#define SEQ 512
// M = BATCH*SEQ = 131072

typedef __attribute__((ext_vector_type(8))) short short8;
typedef __attribute__((ext_vector_type(4))) float floatx4;

__device__ __forceinline__ float bf2f(unsigned short u) {
    union { unsigned int i; float f; } x; x.i = ((unsigned int)u) << 16; return x.f;
}
__device__ __forceinline__ unsigned short f2bf(float f) {
    union { float f; unsigned int i; } x; x.f = f;
    unsigned int i = x.i;
    unsigned int lsb = (i >> 16) & 1u;
    i += 0x7fffu + lsb;
    return (unsigned short)(i >> 16);
}

__device__ __forceinline__ float wred_sum(float v) {
    #pragma unroll
    for (int o = 32; o; o >>= 1) v += __shfl_xor(v, o, 64);
    return v;
}

__device__ __forceinline__ void llds16(const void* g, void* l) {
    auto gp = (const __attribute__((address_space(1))) void*)(g);
    auto lp = (__attribute__((address_space(3))) void*)(uintptr_t)(l);
    __builtin_amdgcn_global_load_lds(gp, lp, 16, 0, 0);
}

#define FENCE() asm volatile("" ::: "memory")
#define BARRIER() do { FENCE(); __builtin_amdgcn_s_barrier(); FENCE(); } while (0)

template<int WN>
__device__ __forceinline__ void waitvm() {
    if constexpr (WN == 6)      asm volatile("s_waitcnt vmcnt(6)" ::: "memory");
    else if constexpr (WN == 4) asm volatile("s_waitcnt vmcnt(4)" ::: "memory");
    else if constexpr (WN == 2) asm volatile("s_waitcnt vmcnt(2)" ::: "memory");
    else if constexpr (WN == 0) asm volatile("s_waitcnt vmcnt(0)" ::: "memory");
}

// ---------------- fused scores + softmax: one block per batch, 512 threads ----------------
template<bool F32IN>
__global__ __launch_bounds__(512)
void scores_kernel(const void* __restrict__ s_in_, const float* __restrict__ q,
                   float* __restrict__ dist_out, unsigned short* __restrict__ s_bf_out) {
    const int b = blockIdx.x, t = threadIdx.x, lane = t & 63, w = t >> 6;
    __shared__ float sc[SEQ];
    __shared__ float red[8];
    __shared__ float m_s, sum_s;

    float qv[8];
    {
        const float4* qp = (const float4*)(q + (size_t)b * D + lane * 8);
        float4 a = qp[0], c = qp[1];
        qv[0] = a.x; qv[1] = a.y; qv[2] = a.z; qv[3] = a.w;
        qv[4] = c.x; qv[5] = c.y; qv[6] = c.z; qv[7] = c.w;
    }
    float qn2 = 0.f;
    #pragma unroll
    for (int j = 0; j < 8; ++j) qn2 += qv[j] * qv[j];
    const float qn = sqrtf(wred_sum(qn2));

    const size_t bbase = (size_t)b * (SEQ * D);
    for (int j = 0; j < 64; j += 2) {
        const int r0 = w * 64 + j;
        float v0[8], v1[8];
        const size_t off0 = bbase + (size_t)r0 * D + lane * 8;
        const size_t off1 = off0 + D;
        if (F32IN) {
            const float4* p0 = (const float4*)((const float*)s_in_ + off0);
            const float4* p1 = (const float4*)((const float*)s_in_ + off1);
            float4 a0 = p0[0], c0 = p0[1], a1 = p1[0], c1 = p1[1];
            v0[0]=a0.x; v0[1]=a0.y; v0[2]=a0.z; v0[3]=a0.w;
            v0[4]=c0.x; v0[5]=c0.y; v0[6]=c0.z; v0[7]=c0.w;
            v1[0]=a1.x; v1[1]=a1.y; v1[2]=a1.z; v1[3]=a1.w;
            v1[4]=c1.x; v1[5]=c1.y; v1[6]=c1.z; v1[7]=c1.w;
            short8 w0, w1;
            #pragma unroll
            for (int k = 0; k < 8; ++k) { w0[k] = (short)f2bf(v0[k]); w1[k] = (short)f2bf(v1[k]); }
            *(short8*)(s_bf_out + off0) = w0;
            *(short8*)(s_bf_out + off1) = w1;
        } else {
            short8 w0 = *(const short8*)((const unsigned short*)s_in_ + off0);
            short8 w1 = *(const short8*)((const unsigned short*)s_in_ + off1);
            #pragma unroll
            for (int k = 0; k < 8; ++k) { v0[k] = bf2f((unsigned short)w0[k]); v1[k] = bf2f((unsigned short)w1[k]); }
        }
        float d0 = 0.f, n0 = 0.f, d1 = 0.f, n1 = 0.f;
        #pragma unroll
        for (int k = 0; k < 8; ++k) {
            d0 += v0[k] * qv[k]; n0 += v0[k] * v0[k];
            d1 += v1[k] * qv[k]; n1 += v1[k] * v1[k];
        }
        d0 = wred_sum(d0); n0 = wred_sum(n0);
        d1 = wred_sum(d1); n1 = wred_sum(n1);
        if (lane == 0) {
            sc[r0]     = 10.f * d0 / fmaxf(qn * sqrtf(n0), 1e-8f);
            sc[r0 + 1] = 10.f * d1 / fmaxf(qn * sqrtf(n1), 1e-8f);
        }
    }
    __syncthreads();

    const float sv = sc[t];
    float m = sv;
    #pragma unroll
    for (int o = 32; o; o >>= 1) m = fmaxf(m, __shfl_xor(m, o, 64));
    if (lane == 0) red[w] = m;
    __syncthreads();
    if (t == 0) {
        float mm = red[0];
        #pragma unroll
        for (int k = 1; k < 8; ++k) mm = fmaxf(mm, red[k]);
        m_s = mm;
    }
    __syncthreads();
    const float e = __expf(sv - m_s);
    float es = wred_sum(e);
    if (lane == 0) red[w] = es;
    __syncthreads();
    if (t == 0) {
        float s = 0.f;
        #pragma unroll
        for (int k = 0; k < 8; ++k) s += red[k];
        sum_s = s;
    }
    __syncthreads();
    dist_out[b * SEQ + t] = e / sum_s;
}

// ---------------- GEMM: 256x256 tile, 8 waves, 4-phase/K-tile counted-vmcnt ----------------
// Wave (wr,wc): m-frag mi -> global row frag fm=mi*2+wr (A-half = mi>>2);
//               n-frag ni -> global col frag fn=ni*4+wc (B-half = ni>>1).
// Phases per K-tile: (mh,nh) = (0,0),(0,1),(1,0),(1,1); stage order A0,B0,B1,A1
// for tile kt+1 -> all waits vmcnt(6) with >=3-phase lag (no drain in main loop).
// LDS swizzle rule#21: chunk (row,c) holds global chunk c^(row&7).
#define NKT 8   // K-tiles of 64

#define STA(BUF, H, KT) { const unsigned short* s_ = pA + (H) * 128 * D + (KT) * 64; \
    llds16(s_, &AsL[BUF][H][t * 8]); llds16(s_ + 64 * D, &AsL[BUF][H][t * 8 + 4096]); }
#define STB(BUF, H, KT) { const unsigned short* s_ = pB + (H) * 128 * D + (KT) * 64; \
    llds16(s_, &BsL[BUF][H][t * 8]); llds16(s_ + 64 * D, &BsL[BUF][H][t * 8 + 4096]); }

#define LDAF(BUF, MH) { _Pragma("unroll") for (int j = 0; j < 4; ++j) { \
    af[j][0] = *(const short8*)&AsL[BUF][MH][aoff[j] + xk0]; \
    af[j][1] = *(const short8*)&AsL[BUF][MH][aoff[j] + xk1]; } }
#define LDBF(BUF, NH) { _Pragma("unroll") for (int i = 0; i < 2; ++i) { \
    bfr[i][0] = *(const short8*)&BsL[BUF][NH][boff[i] + xk0]; \
    bfr[i][1] = *(const short8*)&BsL[BUF][NH][boff[i] + xk1]; } }

#define MMQ(MH, NH) { __builtin_amdgcn_s_setprio(1); \
    _Pragma("unroll") for (int kh = 0; kh < 2; ++kh) \
    _Pragma("unroll") for (int j = 0; j < 4; ++j) \
    _Pragma("unroll") for (int i = 0; i < 2; ++i) \
        acc[(MH) * 4 + j][(NH) * 2 + i] = __builtin_amdgcn_mfma_f32_16x16x32_bf16( \
            af[j][kh], bfr[i][kh], acc[(MH) * 4 + j][(NH) * 2 + i], 0, 0, 0); \
    __builtin_amdgcn_s_setprio(0); }

__global__ __launch_bounds__(512, 2)
void gemm_kernel(const unsigned short* __restrict__ A, const unsigned short* __restrict__ Bt,
                 const float* __restrict__ bias, const float* __restrict__ dist,
                 unsigned short* __restrict__ C, float* __restrict__ part) {
    __shared__ __align__(16) unsigned short AsL[2][2][128 * 64];   // 64 KB
    __shared__ __align__(16) unsigned short BsL[2][2][128 * 64];   // 64 KB
    __shared__ float dls[256];
    __shared__ float agg_lds[2][256];

    const int t = threadIdx.x, lane = t & 63, wid = t >> 6;
    const int wr = wid >> 2, wc = wid & 3;
    const int rr = lane & 15, lg = lane >> 4;
    const int mB = blockIdx.x >> 1, nB = blockIdx.x & 1;
    const size_t tileM = (size_t)mB * 256;
    const int tileN = nB * 256;

    // bias (oldest vmem loads; drained at first counted wait)
    float b_r[4];
    #pragma unroll
    for (int ni = 0; ni < 4; ++ni) b_r[ni] = bias[tileN + (ni * 4 + wc) * 16 + rr];

    // dist -> LDS (lgkm drained before staging so vmcnt bookkeeping starts clean)
    if (t < 128) {
        float2 v = *(const float2*)&dist[tileM + 2 * t];
        dls[2 * t] = v.x; dls[2 * t + 1] = v.y;
    }
    asm volatile("s_waitcnt lgkmcnt(0)" ::: "memory");

    // staging source bases (inverse-swizzled global source, rule #21)
    const int srow = t >> 3, gc = (t & 7) ^ (srow & 7);
    const unsigned short* pA = A + (tileM + srow) * D + gc * 8;
    const unsigned short* pB = Bt + (size_t)(tileN + srow) * D + gc * 8;

    // fragment read offsets (shorts); swizzled k-chunk xor
    int aoff[4], boff[2];
    #pragma unroll
    for (int j = 0; j < 4; ++j) aoff[j] = ((j * 2 + wr) * 16 + rr) * 64;
    #pragma unroll
    for (int i = 0; i < 2; ++i) boff[i] = ((i * 4 + wc) * 16 + rr) * 64;
    const int xk0 = ((lg) ^ (rr & 7)) * 8;
    const int xk1 = ((4 + lg) ^ (rr & 7)) * 8;

    floatx4 acc[8][4];
    #pragma unroll
    for (int i = 0; i < 8; ++i)
        #pragma unroll
        for (int j = 0; j < 4; ++j) acc[i][j] = {0.f, 0.f, 0.f, 0.f};

    short8 af[4][2], bfr[2][2];

    // prologue: tile 0 halves, order A0,B0,B1,A1
    STA(0, 0, 0); STB(0, 0, 0); STB(0, 1, 0); STA(0, 1, 0);

    for (int kt = 0; kt < NKT - 1; ++kt) {
        const int rb = kt & 1, sb = rb ^ 1, nk = kt + 1;
        // p0: quadrant (0,0); stage A0 of kt+1
        STA(sb, 0, nk); waitvm<6>(); BARRIER();
        LDAF(rb, 0); LDBF(rb, 0); MMQ(0, 0); BARRIER();
        // p1: quadrant (0,1); stage B0
        STB(sb, 0, nk); waitvm<6>(); BARRIER();
        LDBF(rb, 1); MMQ(0, 1); BARRIER();
        // p2: quadrant (1,0); stage B1
        STB(sb, 1, nk); waitvm<6>(); BARRIER();
        LDAF(rb, 1); LDBF(rb, 0); MMQ(1, 0); BARRIER();
        // p3: quadrant (1,1); stage A1
        STA(sb, 1, nk); BARRIER();
        LDBF(rb, 1); MMQ(1, 1); BARRIER();
    }
    {   // last tile (kt = 7, rb = 1): counted drain in the tail only
        waitvm<4>(); BARRIER();
        LDAF(1, 0); LDBF(1, 0); MMQ(0, 0); BARRIER();
        waitvm<2>(); BARRIER();
        LDBF(1, 1); MMQ(0, 1); BARRIER();
        waitvm<0>(); BARRIER();
        LDAF(1, 1); LDBF(1, 0); MMQ(1, 0); BARRIER();
        LDBF(1, 1); MMQ(1, 1);
    }
    __syncthreads();

    // epilogue: bias + lrelu + C store + fused agg partials
    float pacc[4] = {0.f, 0.f, 0.f, 0.f};
    #pragma unroll
    for (int mi = 0; mi < 8; ++mi) {
        const int rowb = (mi * 2 + wr) * 16 + lg * 4;
        const float4 dv = *(const float4*)&dls[rowb];
        #pragma unroll
        for (int ni = 0; ni < 4; ++ni) {
            const int col = tileN + (ni * 4 + wc) * 16 + rr;
            #pragma unroll
            for (int r2 = 0; r2 < 4; ++r2) {
                float v = acc[mi][ni][r2] + b_r[ni];
                v = v >= 0.f ? v : 0.01f * v;
                C[(tileM + rowb + r2) * D + col] = f2bf(v);
                pacc[ni] += (&dv.x)[r2] * v;
            }
        }
    }
    #pragma unroll
    for (int ni = 0; ni < 4; ++ni) {
        float p = pacc[ni];
        p += __shfl_xor(p, 16, 64);
        p += __shfl_xor(p, 32, 64);
        if (lg == 0) agg_lds[wr][(ni * 4 + wc) * 16 + rr] = p;
    }
    __syncthreads();
    if (t < 256) {
        const int b = mB >> 1;
        const float s = agg_lds[0][t] + agg_lds[1][t];
        part[(size_t)(mB & 1) * (BATCH * D) + (size_t)b * D + tileN + t] = s;
    }
}

// ---------------- agg partial reduce + residual + LayerNorm ----------------
__global__ __launch_bounds__(256)
void aggln_kernel(const float* __restrict__ part, const float* __restrict__ q_in,
                  const float* __restrict__ gamma, const float* __restrict__ beta,
                  float* __restrict__ q_out) {
    const int b = blockIdx.x, t = threadIdx.x, lane = t & 63, wv = t >> 6;
    __shared__ float red[8];
    __shared__ float mu_s, rstd_s;

    const int c0 = 2 * t;
    float2 v0 = *(const float2*)(part + (size_t)b * D + c0);
    float2 v1 = *(const float2*)(part + (size_t)(BATCH * D) + (size_t)b * D + c0);
    float x0 = q_in[b * D + c0] + v0.x + v1.x;
    float x1 = q_in[b * D + c0 + 1] + v0.y + v1.y;

    float sm = wred_sum(x0 + x1);
    if (lane == 0) red[wv] = sm;
    __syncthreads();
    if (t == 0) mu_s = (red[0] + red[1] + red[2] + red[3]) * (1.f / 512.f);
    __syncthreads();
    const float mu = mu_s;
    float d0 = x0 - mu, d1 = x1 - mu;
    float vv = wred_sum(d0 * d0 + d1 * d1);
    if (lane == 0) red[wv] = vv;
    __syncthreads();
    if (t == 0) rstd_s = rsqrtf((red[0] + red[1] + red[2] + red[3]) * (1.f / 512.f) + 1e-5f);
    __syncthreads();
    const float rs = rstd_s;
    q_out[b * D + c0]     = d0 * rs * gamma[c0]     + beta[c0];
    q_out[b * D + c0 + 1] = d1 * rs * gamma[c0 + 1] + beta[c0 + 1];
}

// ---------------- W f32 -> bf16 ----------------
__global__ __launch_bounds__(256)
void convw_kernel(const float* __restrict__ W, unsigned short* __restrict__ Wb, int n4) {
    int i = blockIdx.x * 256 + threadIdx.x;
    if (i < n4) {
        float4 v = *(const float4*)(W + (size_t)i * 4);
        ushort4 o;
        o.x = f2bf(v.x); o.y = f2bf(v.y); o.z = f2bf(v.z); o.w = f2bf(v.w);
        *(ushort4*)(Wb + (size_t)i * 4) = o;
    }
}

extern "C" void kernel_launch(void* const* d_in, const int* in_sizes, int n_in,
                              void* d_out, int out_size, void* d_ws, size_t ws_size,
                              hipStream_t stream) {
    const float* query = (const float*)d_in[0];
    const float* state = (const float*)d_in[1];
    const float* W     = (const float*)d_in[2];
    const float* bias  = (const float*)d_in[3];
    const float* gamma = (const float*)d_in[4];
    const float* beta  = (const float*)d_in[5];

    float* out_q    = (float*)d_out;
    float* out_dist = (float*)d_out + BATCH * SEQ;

    char* ws = (char*)d_ws;
    const size_t SBYTES = (size_t)BATCH * SEQ * D * 2;   // 134,217,728
    unsigned short* sA = (unsigned short*)ws;
    unsigned short* sB = (unsigned short*)(ws + SBYTES);
    char* ext = ws + 2 * SBYTES;
    float* dist = (float*)ext;                           // 512 KB
    float* qbuf = (float*)(ext + 524288);                // 512 KB
    float* part = (float*)(ext + 2 * 524288);            // 2 slots * 512 KB = 1 MB
    unsigned short* Wb = (unsigned short*)(ext + 4 * 524288);  // 1.5 MB

    hipMemcpyAsync(qbuf, query, (size_t)BATCH * D * sizeof(float),
                   hipMemcpyDeviceToDevice, stream);
    convw_kernel<<<768, 256, 0, stream>>>(W, Wb, 3 * D * D / 4);

    dim3 ggrid(BATCH * SEQ / 256 * 2);   // (M/256) x (N/256=2) = 1024 blocks

    // hop 0
    scores_kernel<true><<<BATCH, 512, 0, stream>>>(state, qbuf, dist, sA);
    gemm_kernel<<<ggrid, 512, 0, stream>>>(sA, Wb, bias, dist, sB, part);
    aggln_kernel<<<BATCH, 256, 0, stream>>>(part, qbuf, gamma, beta, qbuf);
    // hop 1
    scores_kernel<false><<<BATCH, 512, 0, stream>>>(sB, qbuf, dist, nullptr);
    gemm_kernel<<<ggrid, 512, 0, stream>>>(sB, Wb + D * D, bias + D, dist, sA, part);
    aggln_kernel<<<BATCH, 256, 0, stream>>>(part, qbuf, gamma, beta, qbuf);
    // hop 2
    scores_kernel<false><<<BATCH, 512, 0, stream>>>(sA, qbuf, dist, nullptr);
    gemm_kernel<<<ggrid, 512, 0, stream>>>(sA, Wb + 2 * D * D, bias + 2 * D, dist, sB, part);
    aggln_kernel<<<BATCH, 256, 0, stream>>>(part, qbuf, gamma, beta, out_q);
    // final dist
    scores_kernel<false><<<BATCH, 512, 0, stream>>>(sB, out_q, out_dist, nullptr);
}

// Round 8
// 438.996 us; speedup vs baseline: 1.5848x; 1.1158x over previous
//
#include <hip/hip_runtime.h>
#include <hip/hip_bf16.h>
#include <stdint.h>

#define D 512
#define BATCH 256
#define SEQ 512
// M = BATCH*SEQ = 131072

typedef __attribute__((ext_vector_type(8))) short short8;
typedef __attribute__((ext_vector_type(4))) float floatx4;

__device__ __forceinline__ float bf2f(unsigned short u) {
    union { unsigned int i; float f; } x; x.i = ((unsigned int)u) << 16; return x.f;
}
__device__ __forceinline__ unsigned short f2bf(float f) {
    union { float f; unsigned int i; } x; x.f = f;
    unsigned int i = x.i;
    unsigned int lsb = (i >> 16) & 1u;
    i += 0x7fffu + lsb;
    return (unsigned short)(i >> 16);
}

__device__ __forceinline__ float wred_sum(float v) {
    #pragma unroll
    for (int o = 32; o; o >>= 1) v += __shfl_xor(v, o, 64);
    return v;
}
__device__ __forceinline__ float gred_sum16(float v) {   // reduce within 16-lane group
    #pragma unroll
    for (int o = 8; o; o >>= 1) v += __shfl_xor(v, o, 64);
    return v;
}

__device__ __forceinline__ void llds16(const void* g, void* l) {
    auto gp = (const __attribute__((address_space(1))) void*)(g);
    auto lp = (__attribute__((address_space(3))) void*)(uintptr_t)(l);
    __builtin_amdgcn_global_load_lds(gp, lp, 16, 0, 0);
}

#define FENCE() asm volatile("" ::: "memory")
#define BARRIER() do { FENCE(); __builtin_amdgcn_s_barrier(); FENCE(); } while (0)

template<int WN>
__device__ __forceinline__ void waitvm() {
    if constexpr (WN == 6)      asm volatile("s_waitcnt vmcnt(6)" ::: "memory");
    else if constexpr (WN == 4) asm volatile("s_waitcnt vmcnt(4)" ::: "memory");
    else if constexpr (WN == 2) asm volatile("s_waitcnt vmcnt(2)" ::: "memory");
    else if constexpr (WN == 0) asm volatile("s_waitcnt vmcnt(0)" ::: "memory");
}

// ---------------- hop-0 scores: f32 state, q from global; writes bf16 copy ----------------
// 1024 threads; 16-lane group owns one row; lane ll owns elems j*128+ll*8 (j=0..3).
__global__ __launch_bounds__(1024)
void scores0_kernel(const float* __restrict__ state, const float* __restrict__ query,
                    float* __restrict__ dist_out, unsigned short* __restrict__ s_bf_out) {
    const int b = blockIdx.x, t = threadIdx.x, lane = t & 63, w = t >> 6;
    const int g = lane >> 4, ll = lane & 15;
    __shared__ float sc[SEQ];
    __shared__ float red[8];
    __shared__ float m_s, sum_s;

    float qv[4][8];
    {
        const float* qp = query + (size_t)b * D + ll * 8;
        #pragma unroll
        for (int j = 0; j < 4; ++j) {
            float4 a = *(const float4*)(qp + j * 128);
            float4 c = *(const float4*)(qp + j * 128 + 4);
            qv[j][0]=a.x; qv[j][1]=a.y; qv[j][2]=a.z; qv[j][3]=a.w;
            qv[j][4]=c.x; qv[j][5]=c.y; qv[j][6]=c.z; qv[j][7]=c.w;
        }
    }
    float qn2 = 0.f;
    #pragma unroll
    for (int j = 0; j < 4; ++j)
        #pragma unroll
        for (int e = 0; e < 8; ++e) qn2 += qv[j][e] * qv[j][e];
    const float qn = sqrtf(gred_sum16(qn2));

    const size_t bbase = (size_t)b * (SEQ * D);
    #pragma unroll 2
    for (int i = 0; i < 8; ++i) {
        const int row = w * 32 + i * 4 + g;
        const float* rp = state + bbase + (size_t)row * D + ll * 8;
        unsigned short* op = s_bf_out + bbase + (size_t)row * D + ll * 8;
        float dot = 0.f, nr = 0.f;
        #pragma unroll
        for (int j = 0; j < 4; ++j) {
            float4 a = *(const float4*)(rp + j * 128);
            float4 c = *(const float4*)(rp + j * 128 + 4);
            float v[8] = {a.x, a.y, a.z, a.w, c.x, c.y, c.z, c.w};
            short8 wv;
            #pragma unroll
            for (int e = 0; e < 8; ++e) wv[e] = (short)f2bf(v[e]);
            *(short8*)(op + j * 128) = wv;
            #pragma unroll
            for (int e = 0; e < 8; ++e) { dot += v[e] * qv[j][e]; nr += v[e] * v[e]; }
        }
        dot = gred_sum16(dot);
        nr  = gred_sum16(nr);
        if (ll == 0) sc[row] = 10.f * dot / fmaxf(qn * sqrtf(nr), 1e-8f);
    }
    __syncthreads();

    float sv = 0.f, ev = 0.f;
    if (t < 512) {
        sv = sc[t];
        float m = sv;
        #pragma unroll
        for (int o = 32; o; o >>= 1) m = fmaxf(m, __shfl_xor(m, o, 64));
        if (lane == 0) red[w] = m;
    }
    __syncthreads();
    if (t == 0) {
        float mm = red[0];
        #pragma unroll
        for (int k = 1; k < 8; ++k) mm = fmaxf(mm, red[k]);
        m_s = mm;
    }
    __syncthreads();
    if (t < 512) {
        ev = __expf(sv - m_s);
        float es = wred_sum(ev);
        if (lane == 0) red[w] = es;
    }
    __syncthreads();
    if (t == 0) {
        float s = 0.f;
        #pragma unroll
        for (int k = 0; k < 8; ++k) s += red[k];
        sum_s = s;
    }
    __syncthreads();
    if (t < 512) dist_out[b * SEQ + t] = ev / sum_s;
}

// ---------------- fused: agg-reduce + residual + LayerNorm + scores + softmax ----------------
__global__ __launch_bounds__(1024)
void fused_kernel(const unsigned short* __restrict__ S, const float* __restrict__ part,
                  const float* __restrict__ q_in, const float* __restrict__ gamma,
                  const float* __restrict__ beta, float* __restrict__ q_out,
                  float* __restrict__ dist_out) {
    const int b = blockIdx.x, t = threadIdx.x, lane = t & 63, w = t >> 6;
    const int g = lane >> 4, ll = lane & 15;
    __shared__ float qs[D];
    __shared__ float sc[SEQ];
    __shared__ float red[8];
    __shared__ float mu_s, rstd_s, qn_s, m_s, sum_s;

    // --- aggln phase (t < 512) ---
    float x = 0.f;
    if (t < 512) {
        const float a = part[(size_t)b * D + t] + part[(size_t)(BATCH * D) + (size_t)b * D + t];
        x = q_in[(size_t)b * D + t] + a;
        float sm = wred_sum(x);
        if (lane == 0) red[w] = sm;
    }
    __syncthreads();
    if (t == 0) mu_s = (red[0]+red[1]+red[2]+red[3]+red[4]+red[5]+red[6]+red[7]) * (1.f / 512.f);
    __syncthreads();
    if (t < 512) {
        const float d = x - mu_s;
        float vv = wred_sum(d * d);
        if (lane == 0) red[w] = vv;
    }
    __syncthreads();
    if (t == 0) rstd_s = rsqrtf((red[0]+red[1]+red[2]+red[3]+red[4]+red[5]+red[6]+red[7]) * (1.f / 512.f) + 1e-5f);
    __syncthreads();
    if (t < 512) {
        const float y = (x - mu_s) * rstd_s * gamma[t] + beta[t];
        q_out[(size_t)b * D + t] = y;
        qs[t] = y;
        float s2 = wred_sum(y * y);
        if (lane == 0) red[w] = s2;
    }
    __syncthreads();
    if (t == 0) qn_s = sqrtf(red[0]+red[1]+red[2]+red[3]+red[4]+red[5]+red[6]+red[7]);
    __syncthreads();

    // --- scores phase (all 16 waves) ---
    float qv[4][8];
    #pragma unroll
    for (int j = 0; j < 4; ++j) {
        float4 a = *(const float4*)&qs[j * 128 + ll * 8];
        float4 c = *(const float4*)&qs[j * 128 + ll * 8 + 4];
        qv[j][0]=a.x; qv[j][1]=a.y; qv[j][2]=a.z; qv[j][3]=a.w;
        qv[j][4]=c.x; qv[j][5]=c.y; qv[j][6]=c.z; qv[j][7]=c.w;
    }
    const float qn = qn_s;
    const size_t bbase = (size_t)b * (SEQ * D);
    #pragma unroll 2
    for (int i = 0; i < 8; ++i) {
        const int row = w * 32 + i * 4 + g;
        const unsigned short* rp = S + bbase + (size_t)row * D + ll * 8;
        float dot = 0.f, nr = 0.f;
        #pragma unroll
        for (int j = 0; j < 4; ++j) {
            short8 wv = *(const short8*)(rp + j * 128);
            #pragma unroll
            for (int e = 0; e < 8; ++e) {
                const float v = bf2f((unsigned short)wv[e]);
                dot += v * qv[j][e];
                nr += v * v;
            }
        }
        dot = gred_sum16(dot);
        nr  = gred_sum16(nr);
        if (ll == 0) sc[row] = 10.f * dot / fmaxf(qn * sqrtf(nr), 1e-8f);
    }
    __syncthreads();

    float sv = 0.f, ev = 0.f;
    if (t < 512) {
        sv = sc[t];
        float m = sv;
        #pragma unroll
        for (int o = 32; o; o >>= 1) m = fmaxf(m, __shfl_xor(m, o, 64));
        if (lane == 0) red[w] = m;
    }
    __syncthreads();
    if (t == 0) {
        float mm = red[0];
        #pragma unroll
        for (int k = 1; k < 8; ++k) mm = fmaxf(mm, red[k]);
        m_s = mm;
    }
    __syncthreads();
    if (t < 512) {
        ev = __expf(sv - m_s);
        float es = wred_sum(ev);
        if (lane == 0) red[w] = es;
    }
    __syncthreads();
    if (t == 0) {
        float s = 0.f;
        #pragma unroll
        for (int k = 0; k < 8; ++k) s += red[k];
        sum_s = s;
    }
    __syncthreads();
    if (t < 512) dist_out[b * SEQ + t] = ev / sum_s;
}

// ---------------- GEMM: 256x256 tile, 8 waves, 4-phase/K-tile counted-vmcnt ----------------
#define NKT 8   // K-tiles of 64

#define STA(BUF, H, KT) { const unsigned short* s_ = pA + (H) * 128 * D + (KT) * 64; \
    llds16(s_, &AsL[BUF][H][t * 8]); llds16(s_ + 64 * D, &AsL[BUF][H][t * 8 + 4096]); }
#define STB(BUF, H, KT) { const unsigned short* s_ = pB + (H) * 128 * D + (KT) * 64; \
    llds16(s_, &BsL[BUF][H][t * 8]); llds16(s_ + 64 * D, &BsL[BUF][H][t * 8 + 4096]); }

#define LDAF(BUF, MH) { _Pragma("unroll") for (int j = 0; j < 4; ++j) { \
    af[j][0] = *(const short8*)&AsL[BUF][MH][aoff[j] + xk0]; \
    af[j][1] = *(const short8*)&AsL[BUF][MH][aoff[j] + xk1]; } }
#define LDBF(BUF, NH) { _Pragma("unroll") for (int i = 0; i < 2; ++i) { \
    bfr[i][0] = *(const short8*)&BsL[BUF][NH][boff[i] + xk0]; \
    bfr[i][1] = *(const short8*)&BsL[BUF][NH][boff[i] + xk1]; } }

#define MMQ(MH, NH) { __builtin_amdgcn_s_setprio(1); \
    _Pragma("unroll") for (int kh = 0; kh < 2; ++kh) \
    _Pragma("unroll") for (int j = 0; j < 4; ++j) \
    _Pragma("unroll") for (int i = 0; i < 2; ++i) \
        acc[(MH) * 4 + j][(NH) * 2 + i] = __builtin_amdgcn_mfma_f32_16x16x32_bf16( \
            af[j][kh], bfr[i][kh], acc[(MH) * 4 + j][(NH) * 2 + i], 0, 0, 0); \
    __builtin_amdgcn_s_setprio(0); }

__global__ __launch_bounds__(512, 2)
void gemm_kernel(const unsigned short* __restrict__ A, const unsigned short* __restrict__ Bt,
                 const float* __restrict__ bias, const float* __restrict__ dist,
                 unsigned short* __restrict__ C, float* __restrict__ part) {
    __shared__ __align__(16) unsigned short AsL[2][2][128 * 64];   // 64 KB
    __shared__ __align__(16) unsigned short BsL[2][2][128 * 64];   // 64 KB
    __shared__ float dls[256];
    __shared__ float agg_lds[2][256];

    const int t = threadIdx.x, lane = t & 63, wid = t >> 6;
    const int wr = wid >> 2, wc = wid & 3;
    const int rr = lane & 15, lg = lane >> 4;
    const int mB = blockIdx.x >> 1, nB = blockIdx.x & 1;
    const size_t tileM = (size_t)mB * 256;
    const int tileN = nB * 256;

    float b_r[4];
    #pragma unroll
    for (int ni = 0; ni < 4; ++ni) b_r[ni] = bias[tileN + (ni * 4 + wc) * 16 + rr];

    if (t < 128) {
        float2 v = *(const float2*)&dist[tileM + 2 * t];
        dls[2 * t] = v.x; dls[2 * t + 1] = v.y;
    }
    asm volatile("s_waitcnt lgkmcnt(0)" ::: "memory");

    const int srow = t >> 3, gc = (t & 7) ^ (srow & 7);
    const unsigned short* pA = A + (tileM + srow) * D + gc * 8;
    const unsigned short* pB = Bt + (size_t)(tileN + srow) * D + gc * 8;

    int aoff[4], boff[2];
    #pragma unroll
    for (int j = 0; j < 4; ++j) aoff[j] = ((j * 2 + wr) * 16 + rr) * 64;
    #pragma unroll
    for (int i = 0; i < 2; ++i) boff[i] = ((i * 4 + wc) * 16 + rr) * 64;
    const int xk0 = ((lg) ^ (rr & 7)) * 8;
    const int xk1 = ((4 + lg) ^ (rr & 7)) * 8;

    floatx4 acc[8][4];
    #pragma unroll
    for (int i = 0; i < 8; ++i)
        #pragma unroll
        for (int j = 0; j < 4; ++j) acc[i][j] = {0.f, 0.f, 0.f, 0.f};

    short8 af[4][2], bfr[2][2];

    STA(0, 0, 0); STB(0, 0, 0); STB(0, 1, 0); STA(0, 1, 0);

    for (int kt = 0; kt < NKT - 1; ++kt) {
        const int rb = kt & 1, sb = rb ^ 1, nk = kt + 1;
        STA(sb, 0, nk); waitvm<6>(); BARRIER();
        LDAF(rb, 0); LDBF(rb, 0); MMQ(0, 0); BARRIER();
        STB(sb, 0, nk); waitvm<6>(); BARRIER();
        LDBF(rb, 1); MMQ(0, 1); BARRIER();
        STB(sb, 1, nk); waitvm<6>(); BARRIER();
        LDAF(rb, 1); LDBF(rb, 0); MMQ(1, 0); BARRIER();
        STA(sb, 1, nk); BARRIER();
        LDBF(rb, 1); MMQ(1, 1); BARRIER();
    }
    {
        waitvm<4>(); BARRIER();
        LDAF(1, 0); LDBF(1, 0); MMQ(0, 0); BARRIER();
        waitvm<2>(); BARRIER();
        LDBF(1, 1); MMQ(0, 1); BARRIER();
        waitvm<0>(); BARRIER();
        LDAF(1, 1); LDBF(1, 0); MMQ(1, 0); BARRIER();
        LDBF(1, 1); MMQ(1, 1);
    }
    __syncthreads();

    float pacc[4] = {0.f, 0.f, 0.f, 0.f};
    #pragma unroll
    for (int mi = 0; mi < 8; ++mi) {
        const int rowb = (mi * 2 + wr) * 16 + lg * 4;
        const float4 dv = *(const float4*)&dls[rowb];
        #pragma unroll
        for (int ni = 0; ni < 4; ++ni) {
            const int col = tileN + (ni * 4 + wc) * 16 + rr;
            #pragma unroll
            for (int r2 = 0; r2 < 4; ++r2) {
                float v = acc[mi][ni][r2] + b_r[ni];
                v = v >= 0.f ? v : 0.01f * v;
                C[(tileM + rowb + r2) * D + col] = f2bf(v);
                pacc[ni] += (&dv.x)[r2] * v;
            }
        }
    }
    #pragma unroll
    for (int ni = 0; ni < 4; ++ni) {
        float p = pacc[ni];
        p += __shfl_xor(p, 16, 64);
        p += __shfl_xor(p, 32, 64);
        if (lg == 0) agg_lds[wr][(ni * 4 + wc) * 16 + rr] = p;
    }
    __syncthreads();
    if (t < 256) {
        const int b = mB >> 1;
        const float s = agg_lds[0][t] + agg_lds[1][t];
        part[(size_t)(mB & 1) * (BATCH * D) + (size_t)b * D + tileN + t] = s;
    }
}

// ---------------- W f32 -> bf16 ----------------
__global__ __launch_bounds__(256)
void convw_kernel(const float* __restrict__ W, unsigned short* __restrict__ Wb, int n4) {
    int i = blockIdx.x * 256 + threadIdx.x;
    if (i < n4) {
        float4 v = *(const float4*)(W + (size_t)i * 4);
        ushort4 o;
        o.x = f2bf(v.x); o.y = f2bf(v.y); o.z = f2bf(v.z); o.w = f2bf(v.w);
        *(ushort4*)(Wb + (size_t)i * 4) = o;
    }
}

extern "C" void kernel_launch(void* const* d_in, const int* in_sizes, int n_in,
                              void* d_out, int out_size, void* d_ws, size_t ws_size,
                              hipStream_t stream) {
    const float* query = (const float*)d_in[0];
    const float* state = (const float*)d_in[1];
    const float* W     = (const float*)d_in[2];
    const float* bias  = (const float*)d_in[3];
    const float* gamma = (const float*)d_in[4];
    const float* beta  = (const float*)d_in[5];

    float* out_q    = (float*)d_out;
    float* out_dist = (float*)d_out + BATCH * SEQ;

    char* ws = (char*)d_ws;
    const size_t SBYTES = (size_t)BATCH * SEQ * D * 2;   // 134,217,728
    unsigned short* sA = (unsigned short*)ws;
    unsigned short* sB = (unsigned short*)(ws + SBYTES);
    char* ext = ws + 2 * SBYTES;
    float* dist = (float*)ext;                           // 512 KB
    float* qbuf = (float*)(ext + 524288);                // 512 KB
    float* part = (float*)(ext + 2 * 524288);            // 2 slots * 512 KB = 1 MB
    unsigned short* Wb = (unsigned short*)(ext + 4 * 524288);  // 1.5 MB

    convw_kernel<<<768, 256, 0, stream>>>(W, Wb, 3 * D * D / 4);

    dim3 ggrid(BATCH * SEQ / 256 * 2);   // 1024 blocks

    // hop 0
    scores0_kernel<<<BATCH, 1024, 0, stream>>>(state, query, dist, sA);
    gemm_kernel<<<ggrid, 512, 0, stream>>>(sA, Wb, bias, dist, sB, part);
    // hop 1 (aggln uses q_in = query directly)
    fused_kernel<<<BATCH, 1024, 0, stream>>>(sB, part, query, gamma, beta, qbuf, dist);
    gemm_kernel<<<ggrid, 512, 0, stream>>>(sB, Wb + D * D, bias + D, dist, sA, part);
    // hop 2
    fused_kernel<<<BATCH, 1024, 0, stream>>>(sA, part, qbuf, gamma, beta, qbuf, dist);
    gemm_kernel<<<ggrid, 512, 0, stream>>>(sA, Wb + 2 * D * D, bias + 2 * D, dist, sB, part);
    // hop 3 epilogue: final LN -> out_q, final dist -> out_dist
    fused_kernel<<<BATCH, 1024, 0, stream>>>(sB, part, qbuf, gamma, beta, out_q, out_dist);
}

// Round 9
// 421.843 us; speedup vs baseline: 1.6492x; 1.0407x over previous
//
#include <hip/hip_runtime.h>
#include <hip/hip_bf16.h>
#include <stdint.h>

#define D 512
#define BATCH 256
#define SEQ 512
// M = BATCH*SEQ = 131072

typedef __attribute__((ext_vector_type(8))) short short8;
typedef __attribute__((ext_vector_type(4))) float floatx4;

__device__ __forceinline__ float bf2f(unsigned short u) {
    union { unsigned int i; float f; } x; x.i = ((unsigned int)u) << 16; return x.f;
}
__device__ __forceinline__ unsigned short f2bf(float f) {
    union { float f; unsigned int i; } x; x.f = f;
    unsigned int i = x.i;
    unsigned int lsb = (i >> 16) & 1u;
    i += 0x7fffu + lsb;
    return (unsigned short)(i >> 16);
}

__device__ __forceinline__ float wred_sum(float v) {
    #pragma unroll
    for (int o = 32; o; o >>= 1) v += __shfl_xor(v, o, 64);
    return v;
}
__device__ __forceinline__ float gred_sum16(float v) {   // reduce within 16-lane group
    #pragma unroll
    for (int o = 8; o; o >>= 1) v += __shfl_xor(v, o, 64);
    return v;
}

__device__ __forceinline__ void llds16(const void* g, void* l) {
    auto gp = (const __attribute__((address_space(1))) void*)(g);
    auto lp = (__attribute__((address_space(3))) void*)(uintptr_t)(l);
    __builtin_amdgcn_global_load_lds(gp, lp, 16, 0, 0);
}

#define FENCE() asm volatile("" ::: "memory")
#define BARRIER() do { FENCE(); __builtin_amdgcn_s_barrier(); FENCE(); } while (0)

template<int WN>
__device__ __forceinline__ void waitvm() {
    if constexpr (WN == 6)      asm volatile("s_waitcnt vmcnt(6)" ::: "memory");
    else if constexpr (WN == 4) asm volatile("s_waitcnt vmcnt(4)" ::: "memory");
    else if constexpr (WN == 2) asm volatile("s_waitcnt vmcnt(2)" ::: "memory");
    else if constexpr (WN == 0) asm volatile("s_waitcnt vmcnt(0)" ::: "memory");
}

// ---------------- hop-0 scores: f32 state, q from global; writes bf16 copy ----------------
// Also converts W (f32 -> bf16) spread across the grid: 1 float4 per thread.
__global__ __launch_bounds__(1024)
void scores0_kernel(const float* __restrict__ state, const float* __restrict__ query,
                    float* __restrict__ dist_out, unsigned short* __restrict__ s_bf_out,
                    const float* __restrict__ W, unsigned short* __restrict__ Wb) {
    const int b = blockIdx.x, t = threadIdx.x, lane = t & 63, w = t >> 6;
    const int g = lane >> 4, ll = lane & 15;
    __shared__ float sc[SEQ];
    __shared__ float red[8];
    __shared__ float m_s, sum_s;

    // W conversion slice (3*512*512/4 = 196608 float4s over 256*1024 threads)
    {
        const int wi = b * 1024 + t;
        if (wi < 3 * D * D / 4) {
            float4 v = *(const float4*)(W + (size_t)wi * 4);
            ushort4 o;
            o.x = f2bf(v.x); o.y = f2bf(v.y); o.z = f2bf(v.z); o.w = f2bf(v.w);
            *(ushort4*)(Wb + (size_t)wi * 4) = o;
        }
    }

    float qv[4][8];
    {
        const float* qp = query + (size_t)b * D + ll * 8;
        #pragma unroll
        for (int j = 0; j < 4; ++j) {
            float4 a = *(const float4*)(qp + j * 128);
            float4 c = *(const float4*)(qp + j * 128 + 4);
            qv[j][0]=a.x; qv[j][1]=a.y; qv[j][2]=a.z; qv[j][3]=a.w;
            qv[j][4]=c.x; qv[j][5]=c.y; qv[j][6]=c.z; qv[j][7]=c.w;
        }
    }
    float qn2 = 0.f;
    #pragma unroll
    for (int j = 0; j < 4; ++j)
        #pragma unroll
        for (int e = 0; e < 8; ++e) qn2 += qv[j][e] * qv[j][e];
    const float qn = sqrtf(gred_sum16(qn2));

    const size_t bbase = (size_t)b * (SEQ * D);
    #pragma unroll 2
    for (int i = 0; i < 8; ++i) {
        const int row = w * 32 + i * 4 + g;
        const float* rp = state + bbase + (size_t)row * D + ll * 8;
        unsigned short* op = s_bf_out + bbase + (size_t)row * D + ll * 8;
        float dot = 0.f, nr = 0.f;
        #pragma unroll
        for (int j = 0; j < 4; ++j) {
            float4 a = *(const float4*)(rp + j * 128);
            float4 c = *(const float4*)(rp + j * 128 + 4);
            float v[8] = {a.x, a.y, a.z, a.w, c.x, c.y, c.z, c.w};
            short8 wv;
            #pragma unroll
            for (int e = 0; e < 8; ++e) wv[e] = (short)f2bf(v[e]);
            *(short8*)(op + j * 128) = wv;
            #pragma unroll
            for (int e = 0; e < 8; ++e) { dot += v[e] * qv[j][e]; nr += v[e] * v[e]; }
        }
        dot = gred_sum16(dot);
        nr  = gred_sum16(nr);
        if (ll == 0) sc[row] = 10.f * dot / fmaxf(qn * sqrtf(nr), 1e-8f);
    }
    __syncthreads();

    float sv = 0.f, ev = 0.f;
    if (t < 512) {
        sv = sc[t];
        float m = sv;
        #pragma unroll
        for (int o = 32; o; o >>= 1) m = fmaxf(m, __shfl_xor(m, o, 64));
        if (lane == 0) red[w] = m;
    }
    __syncthreads();
    if (t == 0) {
        float mm = red[0];
        #pragma unroll
        for (int k = 1; k < 8; ++k) mm = fmaxf(mm, red[k]);
        m_s = mm;
    }
    __syncthreads();
    if (t < 512) {
        ev = __expf(sv - m_s);
        float es = wred_sum(ev);
        if (lane == 0) red[w] = es;
    }
    __syncthreads();
    if (t == 0) {
        float s = 0.f;
        #pragma unroll
        for (int k = 0; k < 8; ++k) s += red[k];
        sum_s = s;
    }
    __syncthreads();
    if (t < 512) dist_out[b * SEQ + t] = ev / sum_s;
}

// ---------------- fused: agg-reduce + residual + LayerNorm + scores + softmax ----------------
__global__ __launch_bounds__(1024)
void fused_kernel(const unsigned short* __restrict__ S, const float* __restrict__ part,
                  const float* __restrict__ q_in, const float* __restrict__ gamma,
                  const float* __restrict__ beta, float* __restrict__ q_out,
                  float* __restrict__ dist_out) {
    const int b = blockIdx.x, t = threadIdx.x, lane = t & 63, w = t >> 6;
    const int g = lane >> 4, ll = lane & 15;
    __shared__ float qs[D];
    __shared__ float sc[SEQ];
    __shared__ float red[8];
    __shared__ float mu_s, rstd_s, qn_s, m_s, sum_s;

    float x = 0.f;
    if (t < 512) {
        const float a = part[(size_t)b * D + t] + part[(size_t)(BATCH * D) + (size_t)b * D + t];
        x = q_in[(size_t)b * D + t] + a;
        float sm = wred_sum(x);
        if (lane == 0) red[w] = sm;
    }
    __syncthreads();
    if (t == 0) mu_s = (red[0]+red[1]+red[2]+red[3]+red[4]+red[5]+red[6]+red[7]) * (1.f / 512.f);
    __syncthreads();
    if (t < 512) {
        const float d = x - mu_s;
        float vv = wred_sum(d * d);
        if (lane == 0) red[w] = vv;
    }
    __syncthreads();
    if (t == 0) rstd_s = rsqrtf((red[0]+red[1]+red[2]+red[3]+red[4]+red[5]+red[6]+red[7]) * (1.f / 512.f) + 1e-5f);
    __syncthreads();
    if (t < 512) {
        const float y = (x - mu_s) * rstd_s * gamma[t] + beta[t];
        q_out[(size_t)b * D + t] = y;
        qs[t] = y;
        float s2 = wred_sum(y * y);
        if (lane == 0) red[w] = s2;
    }
    __syncthreads();
    if (t == 0) qn_s = sqrtf(red[0]+red[1]+red[2]+red[3]+red[4]+red[5]+red[6]+red[7]);
    __syncthreads();

    float qv[4][8];
    #pragma unroll
    for (int j = 0; j < 4; ++j) {
        float4 a = *(const float4*)&qs[j * 128 + ll * 8];
        float4 c = *(const float4*)&qs[j * 128 + ll * 8 + 4];
        qv[j][0]=a.x; qv[j][1]=a.y; qv[j][2]=a.z; qv[j][3]=a.w;
        qv[j][4]=c.x; qv[j][5]=c.y; qv[j][6]=c.z; qv[j][7]=c.w;
    }
    const float qn = qn_s;
    const size_t bbase = (size_t)b * (SEQ * D);
    #pragma unroll 2
    for (int i = 0; i < 8; ++i) {
        const int row = w * 32 + i * 4 + g;
        const unsigned short* rp = S + bbase + (size_t)row * D + ll * 8;
        float dot = 0.f, nr = 0.f;
        #pragma unroll
        for (int j = 0; j < 4; ++j) {
            short8 wv = *(const short8*)(rp + j * 128);
            #pragma unroll
            for (int e = 0; e < 8; ++e) {
                const float v = bf2f((unsigned short)wv[e]);
                dot += v * qv[j][e];
                nr += v * v;
            }
        }
        dot = gred_sum16(dot);
        nr  = gred_sum16(nr);
        if (ll == 0) sc[row] = 10.f * dot / fmaxf(qn * sqrtf(nr), 1e-8f);
    }
    __syncthreads();

    float sv = 0.f, ev = 0.f;
    if (t < 512) {
        sv = sc[t];
        float m = sv;
        #pragma unroll
        for (int o = 32; o; o >>= 1) m = fmaxf(m, __shfl_xor(m, o, 64));
        if (lane == 0) red[w] = m;
    }
    __syncthreads();
    if (t == 0) {
        float mm = red[0];
        #pragma unroll
        for (int k = 1; k < 8; ++k) mm = fmaxf(mm, red[k]);
        m_s = mm;
    }
    __syncthreads();
    if (t < 512) {
        ev = __expf(sv - m_s);
        float es = wred_sum(ev);
        if (lane == 0) red[w] = es;
    }
    __syncthreads();
    if (t == 0) {
        float s = 0.f;
        #pragma unroll
        for (int k = 0; k < 8; ++k) s += red[k];
        sum_s = s;
    }
    __syncthreads();
    if (t < 512) dist_out[b * SEQ + t] = ev / sum_s;
}

// ---------------- GEMM: 256x256 tile, 8 waves, 4-phase/K-tile counted-vmcnt ----------------
#define NKT 8   // K-tiles of 64

#define STA(BUF, H, KT) { const unsigned short* s_ = pA + (H) * 128 * D + (KT) * 64; \
    llds16(s_, &AsL[BUF][H][t * 8]); llds16(s_ + 64 * D, &AsL[BUF][H][t * 8 + 4096]); }
#define STB(BUF, H, KT) { const unsigned short* s_ = pB + (H) * 128 * D + (KT) * 64; \
    llds16(s_, &BsL[BUF][H][t * 8]); llds16(s_ + 64 * D, &BsL[BUF][H][t * 8 + 4096]); }

#define LDAF(BUF, MH) { _Pragma("unroll") for (int j = 0; j < 4; ++j) { \
    af[j][0] = *(const short8*)&AsL[BUF][MH][aoff[j] + xk0]; \
    af[j][1] = *(const short8*)&AsL[BUF][MH][aoff[j] + xk1]; } }
#define LDBF(BUF, NH) { _Pragma("unroll") for (int i = 0; i < 2; ++i) { \
    bfr[i][0] = *(const short8*)&BsL[BUF][NH][boff[i] + xk0]; \
    bfr[i][1] = *(const short8*)&BsL[BUF][NH][boff[i] + xk1]; } }

#define MMQ(MH, NH) { __builtin_amdgcn_s_setprio(1); \
    _Pragma("unroll") for (int kh = 0; kh < 2; ++kh) \
    _Pragma("unroll") for (int j = 0; j < 4; ++j) \
    _Pragma("unroll") for (int i = 0; i < 2; ++i) \
        acc[(MH) * 4 + j][(NH) * 2 + i] = __builtin_amdgcn_mfma_f32_16x16x32_bf16( \
            af[j][kh], bfr[i][kh], acc[(MH) * 4 + j][(NH) * 2 + i], 0, 0, 0); \
    __builtin_amdgcn_s_setprio(0); }

__global__ __launch_bounds__(512, 2)
void gemm_kernel(const unsigned short* __restrict__ A, const unsigned short* __restrict__ Bt,
                 const float* __restrict__ bias, const float* __restrict__ dist,
                 unsigned short* __restrict__ C, float* __restrict__ part) {
    __shared__ __align__(16) unsigned short AsL[2][2][128 * 64];   // 64 KB
    __shared__ __align__(16) unsigned short BsL[2][2][128 * 64];   // 64 KB
    __shared__ float dls[256];
    __shared__ float agg_lds[2][256];

    const int t = threadIdx.x, lane = t & 63, wid = t >> 6;
    const int wr = wid >> 2, wc = wid & 3;
    const int rr = lane & 15, lg = lane >> 4;
    // XCD-pairing swizzle: the two blocks sharing an A-panel (same mB, nB=0/1)
    // are 8 dispatch-slots apart -> same XCD -> A L2-shared, HBM-fetched once.
    const int bid = blockIdx.x;
    const int xcd = bid & 7, j8 = bid >> 3;
    const int nB = j8 & 1;
    const int mB = xcd * 64 + (j8 >> 1);
    const size_t tileM = (size_t)mB * 256;
    const int tileN = nB * 256;

    float b_r[4];
    #pragma unroll
    for (int ni = 0; ni < 4; ++ni) b_r[ni] = bias[tileN + (ni * 4 + wc) * 16 + rr];

    if (t < 128) {
        float2 v = *(const float2*)&dist[tileM + 2 * t];
        dls[2 * t] = v.x; dls[2 * t + 1] = v.y;
    }
    asm volatile("s_waitcnt lgkmcnt(0)" ::: "memory");

    const int srow = t >> 3, gc = (t & 7) ^ (srow & 7);
    const unsigned short* pA = A + (tileM + srow) * D + gc * 8;
    const unsigned short* pB = Bt + (size_t)(tileN + srow) * D + gc * 8;

    int aoff[4], boff[2];
    #pragma unroll
    for (int j = 0; j < 4; ++j) aoff[j] = ((j * 2 + wr) * 16 + rr) * 64;
    #pragma unroll
    for (int i = 0; i < 2; ++i) boff[i] = ((i * 4 + wc) * 16 + rr) * 64;
    const int xk0 = ((lg) ^ (rr & 7)) * 8;
    const int xk1 = ((4 + lg) ^ (rr & 7)) * 8;

    floatx4 acc[8][4];
    #pragma unroll
    for (int i = 0; i < 8; ++i)
        #pragma unroll
        for (int j = 0; j < 4; ++j) acc[i][j] = {0.f, 0.f, 0.f, 0.f};

    short8 af[4][2], bfr[2][2];

    STA(0, 0, 0); STB(0, 0, 0); STB(0, 1, 0); STA(0, 1, 0);

    for (int kt = 0; kt < NKT - 1; ++kt) {
        const int rb = kt & 1, sb = rb ^ 1, nk = kt + 1;
        STA(sb, 0, nk); waitvm<6>(); BARRIER();
        LDAF(rb, 0); LDBF(rb, 0); MMQ(0, 0); BARRIER();
        STB(sb, 0, nk); waitvm<6>(); BARRIER();
        LDBF(rb, 1); MMQ(0, 1); BARRIER();
        STB(sb, 1, nk); waitvm<6>(); BARRIER();
        LDAF(rb, 1); LDBF(rb, 0); MMQ(1, 0); BARRIER();
        STA(sb, 1, nk); BARRIER();
        LDBF(rb, 1); MMQ(1, 1); BARRIER();
    }
    {
        waitvm<4>(); BARRIER();
        LDAF(1, 0); LDBF(1, 0); MMQ(0, 0); BARRIER();
        waitvm<2>(); BARRIER();
        LDBF(1, 1); MMQ(0, 1); BARRIER();
        waitvm<0>(); BARRIER();
        LDAF(1, 1); LDBF(1, 0); MMQ(1, 0); BARRIER();
        LDBF(1, 1); MMQ(1, 1);
    }
    __syncthreads();

    float pacc[4] = {0.f, 0.f, 0.f, 0.f};
    #pragma unroll
    for (int mi = 0; mi < 8; ++mi) {
        const int rowb = (mi * 2 + wr) * 16 + lg * 4;
        const float4 dv = *(const float4*)&dls[rowb];
        #pragma unroll
        for (int ni = 0; ni < 4; ++ni) {
            const int col = tileN + (ni * 4 + wc) * 16 + rr;
            #pragma unroll
            for (int r2 = 0; r2 < 4; ++r2) {
                float v = acc[mi][ni][r2] + b_r[ni];
                v = v >= 0.f ? v : 0.01f * v;
                C[(tileM + rowb + r2) * D + col] = f2bf(v);
                pacc[ni] += (&dv.x)[r2] * v;
            }
        }
    }
    #pragma unroll
    for (int ni = 0; ni < 4; ++ni) {
        float p = pacc[ni];
        p += __shfl_xor(p, 16, 64);
        p += __shfl_xor(p, 32, 64);
        if (lg == 0) agg_lds[wr][(ni * 4 + wc) * 16 + rr] = p;
    }
    __syncthreads();
    if (t < 256) {
        const int b = mB >> 1;
        const float s = agg_lds[0][t] + agg_lds[1][t];
        part[(size_t)(mB & 1) * (BATCH * D) + (size_t)b * D + tileN + t] = s;
    }
}

extern "C" void kernel_launch(void* const* d_in, const int* in_sizes, int n_in,
                              void* d_out, int out_size, void* d_ws, size_t ws_size,
                              hipStream_t stream) {
    const float* query = (const float*)d_in[0];
    const float* state = (const float*)d_in[1];
    const float* W     = (const float*)d_in[2];
    const float* bias  = (const float*)d_in[3];
    const float* gamma = (const float*)d_in[4];
    const float* beta  = (const float*)d_in[5];

    float* out_q    = (float*)d_out;
    float* out_dist = (float*)d_out + BATCH * SEQ;

    char* ws = (char*)d_ws;
    const size_t SBYTES = (size_t)BATCH * SEQ * D * 2;   // 134,217,728
    unsigned short* sA = (unsigned short*)ws;
    unsigned short* sB = (unsigned short*)(ws + SBYTES);
    char* ext = ws + 2 * SBYTES;
    float* dist = (float*)ext;                           // 512 KB
    float* qbuf = (float*)(ext + 524288);                // 512 KB
    float* part = (float*)(ext + 2 * 524288);            // 2 slots * 512 KB = 1 MB
    unsigned short* Wb = (unsigned short*)(ext + 4 * 524288);  // 1.5 MB

    dim3 ggrid(BATCH * SEQ / 256 * 2);   // 1024 blocks

    // hop 0 (scores0 also converts W -> bf16)
    scores0_kernel<<<BATCH, 1024, 0, stream>>>(state, query, dist, sA, W, Wb);
    gemm_kernel<<<ggrid, 512, 0, stream>>>(sA, Wb, bias, dist, sB, part);
    // hop 1
    fused_kernel<<<BATCH, 1024, 0, stream>>>(sB, part, query, gamma, beta, qbuf, dist);
    gemm_kernel<<<ggrid, 512, 0, stream>>>(sB, Wb + D * D, bias + D, dist, sA, part);
    // hop 2
    fused_kernel<<<BATCH, 1024, 0, stream>>>(sA, part, qbuf, gamma, beta, qbuf, dist);
    gemm_kernel<<<ggrid, 512, 0, stream>>>(sA, Wb + 2 * D * D, bias + 2 * D, dist, sB, part);
    // hop 3 epilogue: final LN -> out_q, final dist -> out_dist
    fused_kernel<<<BATCH, 1024, 0, stream>>>(sB, part, qbuf, gamma, beta, out_q, out_dist);
}